// Round 6
// baseline (627.097 us; speedup 1.0000x reference)
//
#include <hip/hip_runtime.h>
#include <hip/hip_fp16.h>
#include <math.h>

#define NN 100000
#define EE 3200000
#define ETOT (EE + NN)
#define NEG_SLOPE 0.2f
#define DMAX 96
#define CHUNK 4096
#define NB0 ((ETOT + CHUNK - 1) / CHUNK)  // 806
#define RB 391                            // 256 * 391 >= NN
#define CAP 16384                         // window per coarse bucket (expect ~12.9k, sigma ~114)
#define PREPB 391                         // xh/as1/ad1 prep blocks appended to pass1

typedef _Float16 half8 __attribute__((ext_vector_type(8)));
typedef _Float16 half4v __attribute__((ext_vector_type(4)));
typedef _Float16 half2v __attribute__((ext_vector_type(2)));
typedef float floatx4 __attribute__((ext_vector_type(4)));

// ---------------- helpers ----------------
__device__ __forceinline__ float wsum64(float v) {
#pragma unroll
  for (int o = 32; o; o >>= 1) v += __shfl_xor(v, o);
  return v;
}
__device__ __forceinline__ float lrelu(float v) { return v > 0.f ? v : NEG_SLOPE * v; }
__device__ __forceinline__ float elu1(float v) { return v > 0.f ? v : expm1f(v); }

// ---------------- init: window cursors ----------------
__global__ void k_init(int* __restrict__ ccur) {
  ccur[threadIdx.x] = threadIdx.x * CAP;
}

// ---------------- pass1: edge bucketize + weight prep + xh/as1/ad1 prep ----------------
// blocks [0,NB0): bucketize; [NB0,NB0+192): W1t/W2t fp16 transposes;
// [NB0+192, NB0+192+PREPB): xh = fp16(x), as1/ad1 = x . (W1^T a) per head (exact by linearity).
__global__ __launch_bounds__(256) void k_pass1(const int* __restrict__ ei,
                                               int* __restrict__ ccur,
                                               unsigned* __restrict__ ebuf,
                                               const float* __restrict__ W1,
                                               const float* __restrict__ W2,
                                               _Float16* __restrict__ W1t,
                                               _Float16* __restrict__ W2t,
                                               const float* __restrict__ x,
                                               const float* __restrict__ a_src1,
                                               const float* __restrict__ a_dst1,
                                               _Float16* __restrict__ xh,
                                               float* __restrict__ as1,
                                               float* __restrict__ ad1) {
  __shared__ __align__(16) char smem[26624];
  const int b = blockIdx.x;
  const int t = threadIdx.x;
  if (b < NB0) {
    unsigned* vv = (unsigned*)smem;                        // 16384 B
    unsigned short* cbv = (unsigned short*)(smem + 16384); // 8192 B
    int* h = (int*)(smem + 24576);                         // 1024 B
    int* cur = (int*)(smem + 25600);                       // 1024 B
    h[t] = 0;
    __syncthreads();
    int base = b * CHUNK;
    int lim = base + CHUNK; if (lim > ETOT) lim = ETOT;
    int cnt = lim - base;
    for (int i = t; i < cnt; i += 256) {
      int e = base + i;
      int s, d;
      if (e < EE) { s = ei[e]; d = ei[EE + e]; } else { s = e - EE; d = s; }
      unsigned cb = (unsigned)d / (unsigned)RB;
      unsigned dloc = (unsigned)d - cb * (unsigned)RB;
      vv[i] = (dloc << 17) | (unsigned)s;
      cbv[i] = (unsigned short)cb;
      atomicAdd(&h[cb], 1);
    }
    __syncthreads();
    if (h[t]) cur[t] = atomicAdd(&ccur[t], h[t]);
    __syncthreads();
    for (int i = t; i < cnt; i += 256) {
      int cb = cbv[i];
      int pos = atomicAdd(&cur[cb], 1);
      ebuf[pos] = vv[i];
    }
    return;
  }
  if (b < NB0 + 192) {
    // weight prep: W1t[n][k] = W1[k][n] (32768), W2t[n][k] = W2[k][n] (16384)
    int idx = (b - NB0) * 256 + t;
    if (idx < 32768) {
      int n = idx >> 7, k = idx & 127;
      W1t[idx] = (_Float16)W1[k * 256 + n];
    } else {
      int j = idx - 32768;
      int n = j >> 8, k = j & 255;
      W2t[j] = (_Float16)W2[k * 64 + n];
    }
    return;
  }
  // ---- prep: vs/vd = W1^T a (per head), then per-node xh + as1/ad1 ----
  float* vs = (float*)smem;        // 512 floats
  float* vd = vs + 512;            // 512 floats
  for (int i = t; i < 512; i += 256) {
    int h = i >> 7, k = i & 127;
    const float* wrow = W1 + (size_t)k * 256 + h * 64;
    float ss = 0.f, dd = 0.f;
#pragma unroll 8
    for (int d2 = 0; d2 < 64; ++d2) {
      float wv = wrow[d2];
      ss = fmaf(wv, a_src1[h * 64 + d2], ss);
      dd = fmaf(wv, a_dst1[h * 64 + d2], dd);
    }
    vs[i] = ss; vd[i] = dd;
  }
  __syncthreads();
  const int lane = t & 63;
  const int gw = (b - NB0 - 192) * 4 + (t >> 6);  // 0 .. 4*PREPB-1
  for (int n = gw; n < NN; n += 4 * PREPB) {
    float2 xv = *(const float2*)(x + (size_t)n * 128 + lane * 2);
    half2v hx; hx[0] = (_Float16)xv.x; hx[1] = (_Float16)xv.y;
    *(half2v*)(xh + (size_t)n * 128 + lane * 2) = hx;
    float p[8];
#pragma unroll
    for (int h = 0; h < 4; ++h) {
      p[h]     = xv.x * vs[h * 128 + lane * 2] + xv.y * vs[h * 128 + lane * 2 + 1];
      p[4 + h] = xv.x * vd[h * 128 + lane * 2] + xv.y * vd[h * 128 + lane * 2 + 1];
    }
#pragma unroll
    for (int j = 0; j < 8; ++j) p[j] = wsum64(p[j]);
    if (lane == 0) {
      *(float4*)(as1 + n * 4) = make_float4(p[0], p[1], p[2], p[3]);
      *(float4*)(ad1 + n * 4) = make_float4(p[4], p[5], p[6], p[7]);
    }
  }
}

// ---------------- pass2: per-bucket exact placement via LDS cursors; emits offs+deg+csr ----
__global__ __launch_bounds__(256) void k_pass2(const unsigned* __restrict__ ebuf,
                                               const int* __restrict__ ccur,
                                               int* __restrict__ offs,
                                               int* __restrict__ degarr,
                                               int* __restrict__ csr) {
  __shared__ unsigned ed[CAP];
  __shared__ int hist[RB];
  __shared__ int cur[RB];
  int b = blockIdx.x, t = threadIdx.x;
  int d0 = b * RB;
  int rb = NN - d0; if (rb > RB) rb = RB;
  int w0 = b * CAP;
  int cnt = ccur[b] - w0;
  if (cnt > CAP) cnt = CAP;  // statistical impossibility guard
  for (int j = t; j < rb; j += 256) hist[j] = 0;
  __syncthreads();
  for (int i = t; i < cnt; i += 256) {
    unsigned v = ebuf[w0 + i];
    ed[i] = v;
    atomicAdd(&hist[v >> 17], 1);
  }
  __syncthreads();
  if (t == 0) {
    int run = w0;
    for (int j = 0; j < rb; ++j) { cur[j] = run; run += hist[j]; }
  }
  __syncthreads();
  for (int j = t; j < rb; j += 256) {
    offs[d0 + j] = cur[j];
    degarr[d0 + j] = hist[j];
  }
  __syncthreads();
  for (int i = t; i < cnt; i += 256) {
    unsigned v = ed[i];
    int pos = atomicAdd(&cur[v >> 17], 1);
    csr[pos] = (int)(v & 0x1FFFFu);
  }
}

// ---------------- fused layer1 v2: 16 waves, ONE dst per wave (agg1 TLP) ----------------
// Block = 16 waves (1024 thr) = 16 dst. Phase A: each wave gathers/aggregates its dst
// (byte-identical to verified k_agg1 body) into LDS aggT[16][512]. Phase B: wave w
// computes GEMM1 output col-block w (head w>>2, nt w&3): 4 MFMA + bias + elu ->
// h1eT[16][256]. Phase C: waves 0..3 compute GEMM2 col-block (8 MFMA) + as2/ad2.
// agg never touches HBM; W1t/W2t are L2-hot broadcast reads.
__global__ __launch_bounds__(1024) void k_fused16(const int* __restrict__ offs,
                                                  const int* __restrict__ degarr,
                                                  const int* __restrict__ csr_src,
                                                  const float* __restrict__ a_s,
                                                  const float* __restrict__ a_d,
                                                  const _Float16* __restrict__ xh,
                                                  const _Float16* __restrict__ W1t,
                                                  const _Float16* __restrict__ W2t,
                                                  const float* __restrict__ b1,
                                                  const float* __restrict__ a_src2,
                                                  const float* __restrict__ a_dst2,
                                                  _Float16* __restrict__ h2h,
                                                  float* __restrict__ as_out,
                                                  float* __restrict__ ad_out) {
  __shared__ __align__(16) float alp[16][DMAX][4];   // 24576 B
  __shared__ int sidx[16][DMAX];                     // 6144 B
  __shared__ __align__(16) _Float16 aggT[16][520];   // 16640 B
  __shared__ __align__(16) _Float16 h1eT[16][264];   // 8448 B
  __shared__ float prt[2][4][16];                    // 512 B
  const int wid = threadIdx.x >> 6;    // 0..15, one dst per wave
  const int lane = threadIdx.x & 63;
  const int n0 = blockIdx.x * 16;
  const int g = lane >> 4;       // edge group / quad 0..3
  const int sub = lane & 15;     // dim sub-block / m16
  const _Float16* __restrict__ hb = xh + sub * 8;

  // ---------- phase A: aggregate one dst per wave (verified agg1 body) ----------
  {
    const int n = n0 + wid;
    const int beg = offs[n], deg = degarr[n];
    const float4 ad = *(const float4*)(a_d + n * 4);
    float4 sm = make_float4(0.f, 0.f, 0.f, 0.f);
    for (int d = lane; d < deg; d += 64) {
      int s = csr_src[beg + d];
      float4 as = *(const float4*)(a_s + s * 4);
      float e0 = __expf(lrelu(as.x + ad.x));
      float e1 = __expf(lrelu(as.y + ad.y));
      float e2 = __expf(lrelu(as.z + ad.z));
      float e3 = __expf(lrelu(as.w + ad.w));
      sm.x += e0; sm.y += e1; sm.z += e2; sm.w += e3;
      if (d < DMAX) {
        sidx[wid][d] = s;
        *(float4*)&alp[wid][d][0] = make_float4(e0, e1, e2, e3);
      }
    }
    sm.x = wsum64(sm.x); sm.y = wsum64(sm.y); sm.z = wsum64(sm.z); sm.w = wsum64(sm.w);
    const float4 inv4 = make_float4(1.f / sm.x, 1.f / sm.y, 1.f / sm.z, 1.f / sm.w);
    const int dlim = deg < DMAX ? deg : DMAX;
    for (int d = lane; d < dlim; d += 64) {
      float4 a = *(float4*)&alp[wid][d][0];
      a.x *= inv4.x; a.y *= inv4.y; a.z *= inv4.z; a.w *= inv4.w;
      *(float4*)&alp[wid][d][0] = a;
    }
    float acc[4][8];
#pragma unroll
    for (int h = 0; h < 4; ++h)
#pragma unroll
      for (int j = 0; j < 8; ++j) acc[h][j] = 0.f;
    int d = 0;
    for (; d + 8 <= dlim; d += 8) {
      int i0 = d + g, i1 = d + 4 + g;
      int s0 = sidx[wid][i0], s1 = sidx[wid][i1];
      float4 w0 = *(float4*)&alp[wid][i0][0];
      float4 w1 = *(float4*)&alp[wid][i1][0];
      half8 r0 = *(const half8*)(hb + (size_t)s0 * 128);
      half8 r1 = *(const half8*)(hb + (size_t)s1 * 128);
#pragma unroll
      for (int j = 0; j < 8; ++j) {
        float f0 = (float)r0[j], f1 = (float)r1[j];
        acc[0][j] = fmaf(f0, w0.x, acc[0][j]);
        acc[1][j] = fmaf(f0, w0.y, acc[1][j]);
        acc[2][j] = fmaf(f0, w0.z, acc[2][j]);
        acc[3][j] = fmaf(f0, w0.w, acc[3][j]);
        acc[0][j] = fmaf(f1, w1.x, acc[0][j]);
        acc[1][j] = fmaf(f1, w1.y, acc[1][j]);
        acc[2][j] = fmaf(f1, w1.z, acc[2][j]);
        acc[3][j] = fmaf(f1, w1.w, acc[3][j]);
      }
    }
    if (d + 4 <= dlim) {
      int i0 = d + g;
      int s0 = sidx[wid][i0];
      float4 w0 = *(float4*)&alp[wid][i0][0];
      half8 r0 = *(const half8*)(hb + (size_t)s0 * 128);
#pragma unroll
      for (int j = 0; j < 8; ++j) {
        float f0 = (float)r0[j];
        acc[0][j] = fmaf(f0, w0.x, acc[0][j]);
        acc[1][j] = fmaf(f0, w0.y, acc[1][j]);
        acc[2][j] = fmaf(f0, w0.z, acc[2][j]);
        acc[3][j] = fmaf(f0, w0.w, acc[3][j]);
      }
      d += 4;
    }
    if (d < dlim) {  // remainder 1..3 edges: inactive groups get weight 0
      int idx = d + g;
      bool v = idx < dlim;
      int s = sidx[wid][v ? idx : d];
      float4 w0 = *(float4*)&alp[wid][v ? idx : d][0];
      if (!v) { w0.x = 0.f; w0.y = 0.f; w0.z = 0.f; w0.w = 0.f; }
      half8 r0 = *(const half8*)(hb + (size_t)s * 128);
#pragma unroll
      for (int j = 0; j < 8; ++j) {
        float f0 = (float)r0[j];
        acc[0][j] = fmaf(f0, w0.x, acc[0][j]);
        acc[1][j] = fmaf(f0, w0.y, acc[1][j]);
        acc[2][j] = fmaf(f0, w0.z, acc[2][j]);
        acc[3][j] = fmaf(f0, w0.w, acc[3][j]);
      }
    }
    if (deg > DMAX) {  // overflow fallback: never in practice
      for (int dd = DMAX + g; dd < deg; dd += 4) {
        int s = csr_src[beg + dd];
        float4 as = *(const float4*)(a_s + s * 4);
        float w0x = __expf(lrelu(as.x + ad.x)) * inv4.x;
        float w0y = __expf(lrelu(as.y + ad.y)) * inv4.y;
        float w0z = __expf(lrelu(as.z + ad.z)) * inv4.z;
        float w0w = __expf(lrelu(as.w + ad.w)) * inv4.w;
        half8 r0 = *(const half8*)(hb + (size_t)s * 128);
#pragma unroll
        for (int j = 0; j < 8; ++j) {
          float f0 = (float)r0[j];
          acc[0][j] = fmaf(f0, w0x, acc[0][j]);
          acc[1][j] = fmaf(f0, w0y, acc[1][j]);
          acc[2][j] = fmaf(f0, w0z, acc[2][j]);
          acc[3][j] = fmaf(f0, w0w, acc[3][j]);
        }
      }
    }
    // reduce across 4 edge-groups; g==0 lanes hold the final row slice
#pragma unroll
    for (int h = 0; h < 4; ++h)
#pragma unroll
      for (int j = 0; j < 8; ++j) {
        acc[h][j] += __shfl_xor(acc[h][j], 16);
        acc[h][j] += __shfl_xor(acc[h][j], 32);
      }
    if (g == 0) {
#pragma unroll
      for (int h = 0; h < 4; ++h) {
        half8 o;
#pragma unroll
        for (int j = 0; j < 8; ++j) o[j] = (_Float16)acc[h][j];
        *(half8*)&aggT[wid][h * 128 + sub * 8] = o;
      }
    }
  }
  __syncthreads();

  // ---------- phase B: GEMM1 col-block wid: [16x128] @ [128x16] + bias + elu ----------
  const int m16 = sub, quad = g;
  const int hB = wid >> 2, ntB = wid & 3;  // head, col sub-block
  floatx4 acc1 = (floatx4){0.f, 0.f, 0.f, 0.f};
#pragma unroll
  for (int ks = 0; ks < 4; ++ks) {
    half8 av = *(half8*)&aggT[m16][hB * 128 + ks * 32 + quad * 8];
    half8 bv = *(const half8*)(W1t + (size_t)(hB * 64 + ntB * 16 + m16) * 128 + ks * 32 + quad * 8);
    acc1 = __builtin_amdgcn_mfma_f32_16x16x32_f16(av, bv, acc1, 0, 0, 0);
  }
  {
    float bb = b1[hB * 64 + ntB * 16 + m16];
#pragma unroll
    for (int r = 0; r < 4; ++r)
      h1eT[quad * 4 + r][hB * 64 + ntB * 16 + m16] = (_Float16)elu1(acc1[r] + bb);
  }
  __syncthreads();

  // ---------- phase C: GEMM2 col-block (waves 0..3): [16x256] @ [256x16] + as2/ad2 ----
  if (wid < 4) {
    floatx4 acc2 = (floatx4){0.f, 0.f, 0.f, 0.f};
#pragma unroll
    for (int ks = 0; ks < 8; ++ks) {
      half8 av = *(half8*)&h1eT[m16][ks * 32 + quad * 8];
      half8 bv = *(const half8*)(W2t + (size_t)(wid * 16 + m16) * 256 + ks * 32 + quad * 8);
      acc2 = __builtin_amdgcn_mfma_f32_16x16x32_f16(av, bv, acc2, 0, 0, 0);
    }
    const float a2v = a_src2[wid * 16 + m16];
    const float d2v = a_dst2[wid * 16 + m16];
#pragma unroll
    for (int r = 0; r < 4; ++r) {
      int row = quad * 4 + r;
      h2h[(size_t)(n0 + row) * 64 + wid * 16 + m16] = (_Float16)acc2[r];
      float ps = acc2[r] * a2v, pd = acc2[r] * d2v;
#pragma unroll
      for (int o = 1; o < 16; o <<= 1) { ps += __shfl_xor(ps, o); pd += __shfl_xor(pd, o); }
      if (m16 == 0) { prt[0][wid][row] = ps; prt[1][wid][row] = pd; }
    }
  }
  __syncthreads();
  if (threadIdx.x < 16) {
    int row = threadIdx.x;
    as_out[n0 + row] = prt[0][0][row] + prt[0][1][row] + prt[0][2][row] + prt[0][3][row];
    ad_out[n0 + row] = prt[1][0][row] + prt[1][1][row] + prt[1][2][row] + prt[1][3][row];
  }
}

// ---------------- fused attention layer 2 + final linear ----------------
__global__ __launch_bounds__(256) void k_attn2(const int* __restrict__ offs,
                                               const int* __restrict__ degarr,
                                               const int* __restrict__ csr_src,
                                               const float* __restrict__ a_s,
                                               const float* __restrict__ a_d,
                                               const _Float16* __restrict__ h2h,
                                               const float* __restrict__ b2,
                                               const float* __restrict__ lin_w,
                                               const float* __restrict__ lin_b,
                                               float* __restrict__ out) {
  __shared__ float alpha2[4][DMAX];
  __shared__ int sidx2[4][DMAX];
  const int wid = threadIdx.x >> 6;
  const int n = blockIdx.x * 4 + wid;
  const int lane = threadIdx.x & 63;
  const int beg = offs[n], deg = degarr[n];
  const float adn = a_d[n];
  float sm = 0.f;
  for (int d = lane; d < deg; d += 64) {
    int s = csr_src[beg + d];
    float e = __expf(lrelu(a_s[s] + adn));
    sm += e;
    if (d < DMAX) { sidx2[wid][d] = s; alpha2[wid][d] = e; }
  }
  sm = wsum64(sm);
  const float inv = 1.f / sm;
  const int dlim = deg < DMAX ? deg : DMAX;
  for (int d = lane; d < dlim; d += 64) alpha2[wid][d] *= inv;
  const int g = lane >> 4;       // edge group 0..3
  const int sub = lane & 15;     // dims sub*4 .. sub*4+3
  const _Float16* __restrict__ hb = h2h + sub * 4;
  float a0 = 0.f, a1 = 0.f, a2 = 0.f, a3 = 0.f;
  int d = 0;
  for (; d + 8 <= dlim; d += 8) {
    int i0 = d + g, i1 = d + 4 + g;
    int s0 = sidx2[wid][i0], s1 = sidx2[wid][i1];
    float w0 = alpha2[wid][i0], w1 = alpha2[wid][i1];
    half4v r0 = *(const half4v*)(hb + (size_t)s0 * 64);
    half4v r1 = *(const half4v*)(hb + (size_t)s1 * 64);
    a0 = fmaf((float)r0[0], w0, a0); a1 = fmaf((float)r0[1], w0, a1);
    a2 = fmaf((float)r0[2], w0, a2); a3 = fmaf((float)r0[3], w0, a3);
    a0 = fmaf((float)r1[0], w1, a0); a1 = fmaf((float)r1[1], w1, a1);
    a2 = fmaf((float)r1[2], w1, a2); a3 = fmaf((float)r1[3], w1, a3);
  }
  if (d + 4 <= dlim) {
    int i0 = d + g;
    int s0 = sidx2[wid][i0];
    float w0 = alpha2[wid][i0];
    half4v r0 = *(const half4v*)(hb + (size_t)s0 * 64);
    a0 = fmaf((float)r0[0], w0, a0); a1 = fmaf((float)r0[1], w0, a1);
    a2 = fmaf((float)r0[2], w0, a2); a3 = fmaf((float)r0[3], w0, a3);
    d += 4;
  }
  if (d < dlim) {  // remainder 1..3 edges: inactive groups get weight 0
    int idx = d + g;
    bool v = idx < dlim;
    int s = sidx2[wid][v ? idx : d];
    float w = v ? alpha2[wid][idx] : 0.f;
    half4v r = *(const half4v*)(hb + (size_t)s * 64);
    a0 = fmaf((float)r[0], w, a0); a1 = fmaf((float)r[1], w, a1);
    a2 = fmaf((float)r[2], w, a2); a3 = fmaf((float)r[3], w, a3);
  }
  if (deg > DMAX && g == 0) {  // overflow fallback: never in practice
    for (int dd = DMAX; dd < deg; ++dd) {
      int s = csr_src[beg + dd];
      float w = __expf(lrelu(a_s[s] + adn)) * inv;
      half4v r = *(const half4v*)(hb + (size_t)s * 64);
      a0 = fmaf((float)r[0], w, a0); a1 = fmaf((float)r[1], w, a1);
      a2 = fmaf((float)r[2], w, a2); a3 = fmaf((float)r[3], w, a3);
    }
  }
  // combine the 4 edge-groups (lane bits 4 and 5)
  a0 += __shfl_xor(a0, 16); a1 += __shfl_xor(a1, 16);
  a2 += __shfl_xor(a2, 16); a3 += __shfl_xor(a3, 16);
  a0 += __shfl_xor(a0, 32); a1 += __shfl_xor(a1, 32);
  a2 += __shfl_xor(a2, 32); a3 += __shfl_xor(a3, 32);
  const int c = sub * 4;
  float4 bb = *(const float4*)(b2 + c);
  float o0 = elu1(a0 + bb.x);
  float o1 = elu1(a1 + bb.y);
  float o2 = elu1(a2 + bb.z);
  float o3 = elu1(a3 + bb.w);
  float4 lw0 = *(const float4*)(lin_w + c * 2);
  float4 lw1 = *(const float4*)(lin_w + c * 2 + 4);
  float p0 = o0 * lw0.x + o1 * lw0.z + o2 * lw1.x + o3 * lw1.z;
  float p1 = o0 * lw0.y + o1 * lw0.w + o2 * lw1.y + o3 * lw1.w;
  p0 = wsum64(p0) * 0.25f;  // each dim-partial appears in 4 lane-groups
  p1 = wsum64(p1) * 0.25f;
  if (lane == 0) {
    out[n * 2 + 0] = p0 + lin_b[0];
    out[n * 2 + 1] = p1 + lin_b[1];
  }
}

// ---------------- launch ----------------
extern "C" void kernel_launch(void* const* d_in, const int* in_sizes, int n_in,
                              void* d_out, int out_size, void* d_ws, size_t ws_size,
                              hipStream_t stream) {
  const float* x      = (const float*)d_in[0];
  const int*   ei     = (const int*)d_in[1];
  const float* W1     = (const float*)d_in[2];
  const float* a_src1 = (const float*)d_in[3];
  const float* a_dst1 = (const float*)d_in[4];
  const float* b1     = (const float*)d_in[5];
  const float* W2     = (const float*)d_in[6];
  const float* a_src2 = (const float*)d_in[7];
  const float* a_dst2 = (const float*)d_in[8];
  const float* b2     = (const float*)d_in[9];
  const float* lin_w  = (const float*)d_in[10];
  const float* lin_b  = (const float*)d_in[11];
  float* outp = (float*)d_out;

  // Workspace (~78 MB, no overlaps).
  char* w = (char*)d_ws;
  _Float16* xh   = (_Float16*)(w + 0);             // 25,600,000
  _Float16* h2h  = (_Float16*)(w + 25600000);      // 12,800,000
  unsigned* ebuf = (unsigned*)(w + 38400000);      // 16,777,216
  int*    csr    = (int*)(w + 55177216);           // 16,777,216
  _Float16* W1t  = (_Float16*)(w + 71954432);      // 65,536
  _Float16* W2t  = (_Float16*)(w + 72019968);      // 32,768
  float*  as1    = (float*)(w + 72052736);         // 1,600,000
  float*  ad1    = (float*)(w + 73652736);         // 1,600,000
  float*  as2    = (float*)(w + 75252736);         // 400,000
  float*  ad2    = (float*)(w + 75652736);         // 400,000
  int*    offs   = (int*)(w + 76052736);           // 400,000
  int*    degarr = (int*)(w + 76452736);           // 400,000
  int*    ccur   = (int*)(w + 76852736);           // 1,024

  k_init<<<1, 256, 0, stream>>>(ccur);
  k_pass1<<<NB0 + 192 + PREPB, 256, 0, stream>>>(ei, ccur, ebuf, W1, W2, W1t, W2t,
                                                 x, a_src1, a_dst1, xh, as1, ad1);
  k_pass2<<<256, 256, 0, stream>>>(ebuf, ccur, offs, degarr, csr);

  // layer 1 fused: 16 waves/block, 1 dst/wave (agg1 TLP) + in-LDS GEMM1/GEMM2
  k_fused16<<<NN / 16, 1024, 0, stream>>>(offs, degarr, csr, as1, ad1, xh,
                                          W1t, W2t, b1, a_src2, a_dst2, h2h, as2, ad2);

  // layer 2 attention + final linear
  k_attn2<<<NN / 4, 256, 0, stream>>>(offs, degarr, csr, as2, ad2, h2h, b2, lin_w, lin_b, outp);
}

// Round 7
// 507.703 us; speedup vs baseline: 1.2352x; 1.2352x over previous
//
#include <hip/hip_runtime.h>
#include <hip/hip_fp16.h>
#include <math.h>

#define NN 100000
#define EE 3200000
#define ETOT (EE + NN)
#define NEG_SLOPE 0.2f
#define DMAX 96
#define CHUNK 4096
#define NB0 ((ETOT + CHUNK - 1) / CHUNK)  // 806
#define RB 391                            // 256 * 391 >= NN
#define CAP 16384                         // window per coarse bucket (expect ~12.9k, sigma ~114)
#define PREPB 391                         // xh/as1/ad1 prep blocks appended to pass1

typedef _Float16 half8 __attribute__((ext_vector_type(8)));
typedef _Float16 half4v __attribute__((ext_vector_type(4)));
typedef float floatx4 __attribute__((ext_vector_type(4)));

// ---------------- helpers ----------------
__device__ __forceinline__ float wsum64(float v) {
#pragma unroll
  for (int o = 32; o; o >>= 1) v += __shfl_xor(v, o);
  return v;
}
__device__ __forceinline__ float lrelu(float v) { return v > 0.f ? v : NEG_SLOPE * v; }
__device__ __forceinline__ float elu1(float v) { return v > 0.f ? v : expm1f(v); }

// ---------------- init: window cursors ----------------
__global__ void k_init(int* __restrict__ ccur) {
  ccur[threadIdx.x] = threadIdx.x * CAP;
}

// ---------------- pass1: edge bucketize + weight prep + xh/as1/ad1 prep ----------------
// blocks [0,NB0): bucketize; [NB0,NB0+192): W1t/W2t fp16 transposes;
// [NB0+192, NB0+192+PREPB): xh = fp16(x), as1/ad1 = x . (W1^T a) (exact by linearity).
// prep v2: 8 nodes per wave, 8 lanes per node (16 dims each), 3 shuffle rounds per
// reduction instead of 8x wsum64 (48 rounds) -- ~5x fewer wave-cycles, same fp32 math.
__global__ __launch_bounds__(256) void k_pass1(const int* __restrict__ ei,
                                               int* __restrict__ ccur,
                                               unsigned* __restrict__ ebuf,
                                               const float* __restrict__ W1,
                                               const float* __restrict__ W2,
                                               _Float16* __restrict__ W1t,
                                               _Float16* __restrict__ W2t,
                                               const float* __restrict__ x,
                                               const float* __restrict__ a_src1,
                                               const float* __restrict__ a_dst1,
                                               _Float16* __restrict__ xh,
                                               float* __restrict__ as1,
                                               float* __restrict__ ad1) {
  __shared__ __align__(16) char smem[26624];
  const int b = blockIdx.x;
  const int t = threadIdx.x;
  if (b < NB0) {
    unsigned* vv = (unsigned*)smem;                        // 16384 B
    unsigned short* cbv = (unsigned short*)(smem + 16384); // 8192 B
    int* h = (int*)(smem + 24576);                         // 1024 B
    int* cur = (int*)(smem + 25600);                       // 1024 B
    h[t] = 0;
    __syncthreads();
    int base = b * CHUNK;
    int lim = base + CHUNK; if (lim > ETOT) lim = ETOT;
    int cnt = lim - base;
    for (int i = t; i < cnt; i += 256) {
      int e = base + i;
      int s, d;
      if (e < EE) { s = ei[e]; d = ei[EE + e]; } else { s = e - EE; d = s; }
      unsigned cb = (unsigned)d / (unsigned)RB;
      unsigned dloc = (unsigned)d - cb * (unsigned)RB;
      vv[i] = (dloc << 17) | (unsigned)s;
      cbv[i] = (unsigned short)cb;
      atomicAdd(&h[cb], 1);
    }
    __syncthreads();
    if (h[t]) cur[t] = atomicAdd(&ccur[t], h[t]);
    __syncthreads();
    for (int i = t; i < cnt; i += 256) {
      int cb = cbv[i];
      int pos = atomicAdd(&cur[cb], 1);
      ebuf[pos] = vv[i];
    }
    return;
  }
  if (b < NB0 + 192) {
    // weight prep: W1t[n][k] = W1[k][n] (32768), W2t[n][k] = W2[k][n] (16384)
    int idx = (b - NB0) * 256 + t;
    if (idx < 32768) {
      int n = idx >> 7, k = idx & 127;
      W1t[idx] = (_Float16)W1[k * 256 + n];
    } else {
      int j = idx - 32768;
      int n = j >> 8, k = j & 255;
      W2t[j] = (_Float16)W2[k * 64 + n];
    }
    return;
  }
  // ---- prep: vs/vd = W1^T a (per head, fp32), then per-node xh + as1/ad1 ----
  float* vs = (float*)smem;        // 512 floats
  float* vd = vs + 512;            // 512 floats
  for (int i = t; i < 512; i += 256) {
    int h = i >> 7, k = i & 127;
    const float* wrow = W1 + (size_t)k * 256 + h * 64;
    float ss = 0.f, dd = 0.f;
#pragma unroll 8
    for (int d2 = 0; d2 < 64; ++d2) {
      float wv = wrow[d2];
      ss = fmaf(wv, a_src1[h * 64 + d2], ss);
      dd = fmaf(wv, a_dst1[h * 64 + d2], dd);
    }
    vs[i] = ss; vd[i] = dd;
  }
  __syncthreads();
  const int lane = t & 63;
  const int sub8 = lane >> 3;     // node within 8-group
  const int dl = lane & 7;        // 16-dim slab
  const int gw = (b - NB0 - 192) * 4 + (t >> 6);  // global wave 0..4*PREPB-1
  for (int nb = gw * 8; nb < NN; nb += 4 * PREPB * 8) {
    const int n = nb + sub8;
    const bool ok = n < NN;
    float4 xv[4];
#pragma unroll
    for (int j = 0; j < 4; ++j)
      xv[j] = ok ? *(const float4*)(x + (size_t)n * 128 + dl * 16 + j * 4)
                 : make_float4(0.f, 0.f, 0.f, 0.f);
    const float* xf = (const float*)xv;
    if (ok) {
      half8 h0, h1;
#pragma unroll
      for (int c = 0; c < 8; ++c) { h0[c] = (_Float16)xf[c]; h1[c] = (_Float16)xf[8 + c]; }
      *(half8*)(xh + (size_t)n * 128 + dl * 16) = h0;
      *(half8*)(xh + (size_t)n * 128 + dl * 16 + 8) = h1;
    }
    float p[8];
#pragma unroll
    for (int h = 0; h < 4; ++h) {
      float ss = 0.f, dd = 0.f;
#pragma unroll
      for (int c = 0; c < 16; ++c) {
        float xc = xf[c];
        ss = fmaf(xc, vs[h * 128 + dl * 16 + c], ss);
        dd = fmaf(xc, vd[h * 128 + dl * 16 + c], dd);
      }
      p[h] = ss; p[4 + h] = dd;
    }
#pragma unroll
    for (int j = 0; j < 8; ++j) {       // reduce across the 8 lanes of this node
      p[j] += __shfl_xor(p[j], 1);
      p[j] += __shfl_xor(p[j], 2);
      p[j] += __shfl_xor(p[j], 4);
    }
    if (ok && dl == 0) {
      *(float4*)(as1 + n * 4) = make_float4(p[0], p[1], p[2], p[3]);
      *(float4*)(ad1 + n * 4) = make_float4(p[4], p[5], p[6], p[7]);
    }
  }
}

// ---------------- pass2: per-bucket exact placement via LDS cursors; emits offs+deg+csr ----
__global__ __launch_bounds__(256) void k_pass2(const unsigned* __restrict__ ebuf,
                                               const int* __restrict__ ccur,
                                               int* __restrict__ offs,
                                               int* __restrict__ degarr,
                                               int* __restrict__ csr) {
  __shared__ unsigned ed[CAP];
  __shared__ int hist[RB];
  __shared__ int cur[RB];
  int b = blockIdx.x, t = threadIdx.x;
  int d0 = b * RB;
  int rb = NN - d0; if (rb > RB) rb = RB;
  int w0 = b * CAP;
  int cnt = ccur[b] - w0;
  if (cnt > CAP) cnt = CAP;  // statistical impossibility guard
  for (int j = t; j < rb; j += 256) hist[j] = 0;
  __syncthreads();
  for (int i = t; i < cnt; i += 256) {
    unsigned v = ebuf[w0 + i];
    ed[i] = v;
    atomicAdd(&hist[v >> 17], 1);
  }
  __syncthreads();
  if (t == 0) {
    int run = w0;
    for (int j = 0; j < rb; ++j) { cur[j] = run; run += hist[j]; }
  }
  __syncthreads();
  for (int j = t; j < rb; j += 256) {
    offs[d0 + j] = cur[j];
    degarr[d0 + j] = hist[j];
  }
  __syncthreads();
  for (int i = t; i < cnt; i += 256) {
    unsigned v = ed[i];
    int pos = atomicAdd(&cur[v >> 17], 1);
    csr[pos] = (int)(v & 0x1FFFFu);
  }
}

// ---------------- agg1: per-dst softmax + aggregate fp16(x) rows, all 4 heads ----------
// One wave per dst (verified round 4; 165 us, at the random-gather fill ceiling).
__global__ __launch_bounds__(256) void k_agg1(const int* __restrict__ offs,
                                              const int* __restrict__ degarr,
                                              const int* __restrict__ csr_src,
                                              const float* __restrict__ a_s,
                                              const float* __restrict__ a_d,
                                              const _Float16* __restrict__ xh,
                                              _Float16* __restrict__ agg) {
  __shared__ __align__(16) float alp[4][DMAX][4];
  __shared__ int sidx[4][DMAX];
  const int wid = threadIdx.x >> 6;
  const int n = blockIdx.x * 4 + wid;
  const int lane = threadIdx.x & 63;
  const int beg = offs[n], deg = degarr[n];
  const float4 ad = *(const float4*)(a_d + n * 4);
  float4 sm = make_float4(0.f, 0.f, 0.f, 0.f);
  for (int d = lane; d < deg; d += 64) {
    int s = csr_src[beg + d];
    float4 as = *(const float4*)(a_s + s * 4);
    float e0 = __expf(lrelu(as.x + ad.x));
    float e1 = __expf(lrelu(as.y + ad.y));
    float e2 = __expf(lrelu(as.z + ad.z));
    float e3 = __expf(lrelu(as.w + ad.w));
    sm.x += e0; sm.y += e1; sm.z += e2; sm.w += e3;
    if (d < DMAX) {
      sidx[wid][d] = s;
      *(float4*)&alp[wid][d][0] = make_float4(e0, e1, e2, e3);
    }
  }
  sm.x = wsum64(sm.x); sm.y = wsum64(sm.y); sm.z = wsum64(sm.z); sm.w = wsum64(sm.w);
  const float4 inv4 = make_float4(1.f / sm.x, 1.f / sm.y, 1.f / sm.z, 1.f / sm.w);
  const int dlim = deg < DMAX ? deg : DMAX;
  for (int d = lane; d < dlim; d += 64) {
    float4 a = *(float4*)&alp[wid][d][0];
    a.x *= inv4.x; a.y *= inv4.y; a.z *= inv4.z; a.w *= inv4.w;
    *(float4*)&alp[wid][d][0] = a;
  }
  const int g = lane >> 4;       // edge group 0..3
  const int sub = lane & 15;     // dims sub*8 .. sub*8+7 (16 x 8 = 128)
  const _Float16* __restrict__ hb = xh + sub * 8;
  float acc[4][8];
#pragma unroll
  for (int h = 0; h < 4; ++h)
#pragma unroll
    for (int j = 0; j < 8; ++j) acc[h][j] = 0.f;
  int d = 0;
  for (; d + 8 <= dlim; d += 8) {
    int i0 = d + g, i1 = d + 4 + g;
    int s0 = sidx[wid][i0], s1 = sidx[wid][i1];
    float4 w0 = *(float4*)&alp[wid][i0][0];
    float4 w1 = *(float4*)&alp[wid][i1][0];
    half8 r0 = *(const half8*)(hb + (size_t)s0 * 128);
    half8 r1 = *(const half8*)(hb + (size_t)s1 * 128);
#pragma unroll
    for (int j = 0; j < 8; ++j) {
      float f0 = (float)r0[j], f1 = (float)r1[j];
      acc[0][j] = fmaf(f0, w0.x, acc[0][j]);
      acc[1][j] = fmaf(f0, w0.y, acc[1][j]);
      acc[2][j] = fmaf(f0, w0.z, acc[2][j]);
      acc[3][j] = fmaf(f0, w0.w, acc[3][j]);
      acc[0][j] = fmaf(f1, w1.x, acc[0][j]);
      acc[1][j] = fmaf(f1, w1.y, acc[1][j]);
      acc[2][j] = fmaf(f1, w1.z, acc[2][j]);
      acc[3][j] = fmaf(f1, w1.w, acc[3][j]);
    }
  }
  if (d + 4 <= dlim) {
    int i0 = d + g;
    int s0 = sidx[wid][i0];
    float4 w0 = *(float4*)&alp[wid][i0][0];
    half8 r0 = *(const half8*)(hb + (size_t)s0 * 128);
#pragma unroll
    for (int j = 0; j < 8; ++j) {
      float f0 = (float)r0[j];
      acc[0][j] = fmaf(f0, w0.x, acc[0][j]);
      acc[1][j] = fmaf(f0, w0.y, acc[1][j]);
      acc[2][j] = fmaf(f0, w0.z, acc[2][j]);
      acc[3][j] = fmaf(f0, w0.w, acc[3][j]);
    }
    d += 4;
  }
  if (d < dlim) {  // remainder 1..3 edges: inactive groups get weight 0
    int idx = d + g;
    bool v = idx < dlim;
    int s = sidx[wid][v ? idx : d];
    float4 w0 = *(float4*)&alp[wid][v ? idx : d][0];
    if (!v) { w0.x = 0.f; w0.y = 0.f; w0.z = 0.f; w0.w = 0.f; }
    half8 r0 = *(const half8*)(hb + (size_t)s * 128);
#pragma unroll
    for (int j = 0; j < 8; ++j) {
      float f0 = (float)r0[j];
      acc[0][j] = fmaf(f0, w0.x, acc[0][j]);
      acc[1][j] = fmaf(f0, w0.y, acc[1][j]);
      acc[2][j] = fmaf(f0, w0.z, acc[2][j]);
      acc[3][j] = fmaf(f0, w0.w, acc[3][j]);
    }
  }
  if (deg > DMAX) {  // overflow fallback: never in practice
    for (int dd = DMAX + g; dd < deg; dd += 4) {
      int s = csr_src[beg + dd];
      float4 as = *(const float4*)(a_s + s * 4);
      float w0x = __expf(lrelu(as.x + ad.x)) * inv4.x;
      float w0y = __expf(lrelu(as.y + ad.y)) * inv4.y;
      float w0z = __expf(lrelu(as.z + ad.z)) * inv4.z;
      float w0w = __expf(lrelu(as.w + ad.w)) * inv4.w;
      half8 r0 = *(const half8*)(hb + (size_t)s * 128);
#pragma unroll
      for (int j = 0; j < 8; ++j) {
        float f0 = (float)r0[j];
        acc[0][j] = fmaf(f0, w0x, acc[0][j]);
        acc[1][j] = fmaf(f0, w0y, acc[1][j]);
        acc[2][j] = fmaf(f0, w0z, acc[2][j]);
        acc[3][j] = fmaf(f0, w0w, acc[3][j]);
      }
    }
  }
  // reduce across the 4 edge-groups (lane bits 4,5)
#pragma unroll
  for (int h = 0; h < 4; ++h)
#pragma unroll
    for (int j = 0; j < 8; ++j) {
      acc[h][j] += __shfl_xor(acc[h][j], 16);
      acc[h][j] += __shfl_xor(acc[h][j], 32);
    }
  if (g == 0) {
#pragma unroll
    for (int h = 0; h < 4; ++h) {
      half8 o;
#pragma unroll
      for (int j = 0; j < 8; ++j) o[j] = (_Float16)acc[h][j];
      *(half8*)(agg + ((size_t)n * 4 + h) * 128 + sub * 8) = o;
    }
  }
}

// ---------------- fused GEMMs v2: LDS-staged agg tile, coalesced ----------
// Block = 256 thr, 32 nodes. Stage As[32][512] via coalesced half8 loads (32 KB contig),
// GEMM1 (wave w = head w) -> elu -> h1eT, GEMM2 (wave w = col block w) -> h2h/as2/ad2.
__global__ __launch_bounds__(256) void k_gemmAgg2(const _Float16* __restrict__ agg,
                                                  const _Float16* __restrict__ W1t,
                                                  const _Float16* __restrict__ W2t,
                                                  const float* __restrict__ b1,
                                                  const float* __restrict__ a_src2,
                                                  const float* __restrict__ a_dst2,
                                                  _Float16* __restrict__ h2h,
                                                  float* __restrict__ as_out,
                                                  float* __restrict__ ad_out) {
  __shared__ __align__(16) _Float16 As[32][520];
  __shared__ __align__(16) _Float16 h1eT[32][264];
  __shared__ float prt[2][4][32];
  const int tid = threadIdx.x;
  const int row0 = blockIdx.x * 32;
  // stage: 32 rows x 512 halves = 2048 half8-chunks, coalesced
#pragma unroll
  for (int i = 0; i < 8; ++i) {
    int c = i * 256 + tid;
    int r = c >> 6;
    int c8 = c & 63;
    *(half8*)&As[r][c8 * 8] = *(const half8*)(agg + (size_t)(row0 + r) * 512 + c8 * 8);
  }
  __syncthreads();
  const int wid = tid >> 6, lane = tid & 63;
  const int m16 = lane & 15, quad = lane >> 4;
  // GEMM1: head wid: [32x128] @ [128x64]
  floatx4 acc1[2][4];
#pragma unroll
  for (int mt = 0; mt < 2; ++mt)
#pragma unroll
    for (int nt = 0; nt < 4; ++nt) acc1[mt][nt] = (floatx4){0.f, 0.f, 0.f, 0.f};
#pragma unroll
  for (int mt = 0; mt < 2; ++mt) {
#pragma unroll
    for (int ks = 0; ks < 4; ++ks) {
      half8 av = *(half8*)&As[mt * 16 + m16][wid * 128 + ks * 32 + quad * 8];
#pragma unroll
      for (int nt = 0; nt < 4; ++nt) {
        half8 bv = *(const half8*)(W1t + (size_t)(wid * 64 + nt * 16 + m16) * 128 + ks * 32 + quad * 8);
        acc1[mt][nt] = __builtin_amdgcn_mfma_f32_16x16x32_f16(av, bv, acc1[mt][nt], 0, 0, 0);
      }
    }
  }
#pragma unroll
  for (int mt = 0; mt < 2; ++mt)
#pragma unroll
    for (int nt = 0; nt < 4; ++nt) {
      float bb = b1[wid * 64 + nt * 16 + m16];
#pragma unroll
      for (int r = 0; r < 4; ++r)
        h1eT[mt * 16 + quad * 4 + r][wid * 64 + nt * 16 + m16] = (_Float16)elu1(acc1[mt][nt][r] + bb);
    }
  __syncthreads();
  // GEMM2: col-block wid: [32x256] @ [256x16]
  floatx4 acc2[2];
#pragma unroll
  for (int mt = 0; mt < 2; ++mt) acc2[mt] = (floatx4){0.f, 0.f, 0.f, 0.f};
#pragma unroll
  for (int mt = 0; mt < 2; ++mt) {
#pragma unroll
    for (int ks = 0; ks < 8; ++ks) {
      half8 av = *(half8*)&h1eT[mt * 16 + m16][ks * 32 + quad * 8];
      half8 bv = *(const half8*)(W2t + (size_t)(wid * 16 + m16) * 256 + ks * 32 + quad * 8);
      acc2[mt] = __builtin_amdgcn_mfma_f32_16x16x32_f16(av, bv, acc2[mt], 0, 0, 0);
    }
  }
  const float a2v = a_src2[wid * 16 + m16];
  const float d2v = a_dst2[wid * 16 + m16];
#pragma unroll
  for (int mt = 0; mt < 2; ++mt)
#pragma unroll
    for (int r = 0; r < 4; ++r) {
      int row = mt * 16 + quad * 4 + r;
      h2h[(size_t)(row0 + row) * 64 + wid * 16 + m16] = (_Float16)acc2[mt][r];
      float ps = acc2[mt][r] * a2v, pd = acc2[mt][r] * d2v;
#pragma unroll
      for (int o = 1; o < 16; o <<= 1) { ps += __shfl_xor(ps, o); pd += __shfl_xor(pd, o); }
      if (m16 == 0) { prt[0][wid][row] = ps; prt[1][wid][row] = pd; }
    }
  __syncthreads();
  if (tid < 32) {
    as_out[row0 + tid] = prt[0][0][tid] + prt[0][1][tid] + prt[0][2][tid] + prt[0][3][tid];
    ad_out[row0 + tid] = prt[1][0][tid] + prt[1][1][tid] + prt[1][2][tid] + prt[1][3][tid];
  }
}

// ---------------- fused attention layer 2 + final linear ----------------
__global__ __launch_bounds__(256) void k_attn2(const int* __restrict__ offs,
                                               const int* __restrict__ degarr,
                                               const int* __restrict__ csr_src,
                                               const float* __restrict__ a_s,
                                               const float* __restrict__ a_d,
                                               const _Float16* __restrict__ h2h,
                                               const float* __restrict__ b2,
                                               const float* __restrict__ lin_w,
                                               const float* __restrict__ lin_b,
                                               float* __restrict__ out) {
  __shared__ float alpha2[4][DMAX];
  __shared__ int sidx2[4][DMAX];
  const int wid = threadIdx.x >> 6;
  const int n = blockIdx.x * 4 + wid;
  const int lane = threadIdx.x & 63;
  const int beg = offs[n], deg = degarr[n];
  const float adn = a_d[n];
  float sm = 0.f;
  for (int d = lane; d < deg; d += 64) {
    int s = csr_src[beg + d];
    float e = __expf(lrelu(a_s[s] + adn));
    sm += e;
    if (d < DMAX) { sidx2[wid][d] = s; alpha2[wid][d] = e; }
  }
  sm = wsum64(sm);
  const float inv = 1.f / sm;
  const int dlim = deg < DMAX ? deg : DMAX;
  for (int d = lane; d < dlim; d += 64) alpha2[wid][d] *= inv;
  const int g = lane >> 4;       // edge group 0..3
  const int sub = lane & 15;     // dims sub*4 .. sub*4+3
  const _Float16* __restrict__ hb = h2h + sub * 4;
  float a0 = 0.f, a1 = 0.f, a2 = 0.f, a3 = 0.f;
  int d = 0;
  for (; d + 8 <= dlim; d += 8) {
    int i0 = d + g, i1 = d + 4 + g;
    int s0 = sidx2[wid][i0], s1 = sidx2[wid][i1];
    float w0 = alpha2[wid][i0], w1 = alpha2[wid][i1];
    half4v r0 = *(const half4v*)(hb + (size_t)s0 * 64);
    half4v r1 = *(const half4v*)(hb + (size_t)s1 * 64);
    a0 = fmaf((float)r0[0], w0, a0); a1 = fmaf((float)r0[1], w0, a1);
    a2 = fmaf((float)r0[2], w0, a2); a3 = fmaf((float)r0[3], w0, a3);
    a0 = fmaf((float)r1[0], w1, a0); a1 = fmaf((float)r1[1], w1, a1);
    a2 = fmaf((float)r1[2], w1, a2); a3 = fmaf((float)r1[3], w1, a3);
  }
  if (d + 4 <= dlim) {
    int i0 = d + g;
    int s0 = sidx2[wid][i0];
    float w0 = alpha2[wid][i0];
    half4v r0 = *(const half4v*)(hb + (size_t)s0 * 64);
    a0 = fmaf((float)r0[0], w0, a0); a1 = fmaf((float)r0[1], w0, a1);
    a2 = fmaf((float)r0[2], w0, a2); a3 = fmaf((float)r0[3], w0, a3);
    d += 4;
  }
  if (d < dlim) {  // remainder 1..3 edges: inactive groups get weight 0
    int idx = d + g;
    bool v = idx < dlim;
    int s = sidx2[wid][v ? idx : d];
    float w = v ? alpha2[wid][idx] : 0.f;
    half4v r = *(const half4v*)(hb + (size_t)s * 64);
    a0 = fmaf((float)r[0], w, a0); a1 = fmaf((float)r[1], w, a1);
    a2 = fmaf((float)r[2], w, a2); a3 = fmaf((float)r[3], w, a3);
  }
  if (deg > DMAX && g == 0) {  // overflow fallback: never in practice
    for (int dd = DMAX; dd < deg; ++dd) {
      int s = csr_src[beg + dd];
      float w = __expf(lrelu(a_s[s] + adn)) * inv;
      half4v r = *(const half4v*)(hb + (size_t)s * 64);
      a0 = fmaf((float)r[0], w, a0); a1 = fmaf((float)r[1], w, a1);
      a2 = fmaf((float)r[2], w, a2); a3 = fmaf((float)r[3], w, a3);
    }
  }
  // combine the 4 edge-groups (lane bits 4 and 5)
  a0 += __shfl_xor(a0, 16); a1 += __shfl_xor(a1, 16);
  a2 += __shfl_xor(a2, 16); a3 += __shfl_xor(a3, 16);
  a0 += __shfl_xor(a0, 32); a1 += __shfl_xor(a1, 32);
  a2 += __shfl_xor(a2, 32); a3 += __shfl_xor(a3, 32);
  const int c = sub * 4;
  float4 bb = *(const float4*)(b2 + c);
  float o0 = elu1(a0 + bb.x);
  float o1 = elu1(a1 + bb.y);
  float o2 = elu1(a2 + bb.z);
  float o3 = elu1(a3 + bb.w);
  float4 lw0 = *(const float4*)(lin_w + c * 2);
  float4 lw1 = *(const float4*)(lin_w + c * 2 + 4);
  float p0 = o0 * lw0.x + o1 * lw0.z + o2 * lw1.x + o3 * lw1.z;
  float p1 = o0 * lw0.y + o1 * lw0.w + o2 * lw1.y + o3 * lw1.w;
  p0 = wsum64(p0) * 0.25f;  // each dim-partial appears in 4 lane-groups
  p1 = wsum64(p1) * 0.25f;
  if (lane == 0) {
    out[n * 2 + 0] = p0 + lin_b[0];
    out[n * 2 + 1] = p1 + lin_b[1];
  }
}

// ---------------- launch ----------------
extern "C" void kernel_launch(void* const* d_in, const int* in_sizes, int n_in,
                              void* d_out, int out_size, void* d_ws, size_t ws_size,
                              hipStream_t stream) {
  const float* x      = (const float*)d_in[0];
  const int*   ei     = (const int*)d_in[1];
  const float* W1     = (const float*)d_in[2];
  const float* a_src1 = (const float*)d_in[3];
  const float* a_dst1 = (const float*)d_in[4];
  const float* b1     = (const float*)d_in[5];
  const float* W2     = (const float*)d_in[6];
  const float* a_src2 = (const float*)d_in[7];
  const float* a_dst2 = (const float*)d_in[8];
  const float* b2     = (const float*)d_in[9];
  const float* lin_w  = (const float*)d_in[10];
  const float* lin_b  = (const float*)d_in[11];
  float* outp = (float*)d_out;

  // Workspace (~149.7 MB, round-4 layout). Live intervals:
  // ebuf pass1->pass2 (inside agg slot, dead before agg1 writes agg);
  // xh pass1->agg1; agg agg1->gemmAgg2; h2h gemmAgg2->attn2 (reuses xh slot).
  char* w = (char*)d_ws;
  _Float16* agg  = (_Float16*)(w + 0);             // 102,400,000
  unsigned* ebuf = (unsigned*)(w + 33554432);      // 16,777,216 (inside agg slot)
  _Float16* xh   = (_Float16*)(w + 102400000);     // 25,600,000
  _Float16* h2h  = (_Float16*)(w + 102400000);     // 12,800,000 (reuses xh slot)
  int*    csr    = (int*)(w + 128000000);          // 16,777,216
  _Float16* W1t  = (_Float16*)(w + 144777216);     // 65,536
  _Float16* W2t  = (_Float16*)(w + 144842752);     // 32,768
  float*  as1    = (float*)(w + 144875520);        // 1,600,000
  float*  ad1    = (float*)(w + 146475520);        // 1,600,000
  float*  as2    = (float*)(w + 148075520);        // 400,000
  float*  ad2    = (float*)(w + 148475520);        // 400,000
  int*    offs   = (int*)(w + 148875520);          // 400,000
  int*    degarr = (int*)(w + 149275520);          // 400,000
  int*    ccur   = (int*)(w + 149675520);          // 1,024

  k_init<<<1, 256, 0, stream>>>(ccur);
  k_pass1<<<NB0 + 192 + PREPB, 256, 0, stream>>>(ei, ccur, ebuf, W1, W2, W1t, W2t,
                                                 x, a_src1, a_dst1, xh, as1, ad1);
  k_pass2<<<256, 256, 0, stream>>>(ebuf, ccur, offs, degarr, csr);

  // layer 1: split structure (full TLP gather) + coalesced LDS-staged transform
  k_agg1<<<NN / 4, 256, 0, stream>>>(offs, degarr, csr, as1, ad1, xh, agg);
  k_gemmAgg2<<<NN / 32, 256, 0, stream>>>(agg, W1t, W2t, b1, a_src2, a_dst2, h2h, as2, ad2);

  // layer 2 attention + final linear
  k_attn2<<<NN / 4, 256, 0, stream>>>(offs, degarr, csr, as2, ad2, h2h, b2, lin_w, lin_b, outp);
}